// Round 1
// 306.296 us; speedup vs baseline: 1.0708x; 1.0708x over previous
//
#include <hip/hip_runtime.h>
#include <cstdint>
#include <cstddef>

typedef unsigned short USHORT;
typedef __bf16 bf16x8 __attribute__((ext_vector_type(8)));
typedef float f32x4 __attribute__((ext_vector_type(4)));

__device__ __forceinline__ float b2f(USHORT u) {
    union { unsigned int i; float f; } v; v.i = ((unsigned int)u) << 16; return v.f;
}
__device__ __forceinline__ USHORT f2bf(float f) {
    union { float f; unsigned int i; } v; v.f = f;
    unsigned int u = v.i;
    unsigned int r = (u + 0x7FFFu + ((u >> 16) & 1u)) >> 16;
    return (USHORT)r;
}
__device__ __forceinline__ float fexp2(float x) { return __builtin_amdgcn_exp2f(x); }

__device__ __forceinline__ void gload_lds16(const void* g, void* l) {
    __builtin_amdgcn_global_load_lds(
        (const __attribute__((address_space(1))) void*)(uintptr_t)g,
        (__attribute__((address_space(3))) void*)(uint32_t)(uintptr_t)l,
        16, 0, 0);
}

// ---------------- f32 -> bf16 conversion (weights), 4 elems/thread ----------
__global__ __launch_bounds__(256)
void f2b_kernel(const float* __restrict__ src, USHORT* __restrict__ dst, int n)
{
    int i = (blockIdx.x * 256 + threadIdx.x) * 4;
    if (i < n) {
        float4 v = *(const float4*)(src + i);
        ushort4 o;
        o.x = f2bf(v.x); o.y = f2bf(v.y); o.z = f2bf(v.z); o.w = f2bf(v.w);
        *(ushort4*)(dst + i) = o;
    }
}

// ---------------- LayerNorm: f32 in -> bf16 out. 1 block/token, 256 thr ----
__global__ __launch_bounds__(256)
void ln_kernel(const float* __restrict__ inp, const float* __restrict__ g,
               const float* __restrict__ bsh, USHORT* __restrict__ out)
{
    const int tid = threadIdx.x;
    const size_t row = blockIdx.x;
    float4 t = ((const float4*)inp)[row * 256 + tid];
    float v[4] = { t.x, t.y, t.z, t.w };
    float s = v[0] + v[1] + v[2] + v[3];
    float sq = v[0]*v[0] + v[1]*v[1] + v[2]*v[2] + v[3]*v[3];
    #pragma unroll
    for (int off = 32; off; off >>= 1) { s += __shfl_down(s, off); sq += __shfl_down(sq, off); }
    __shared__ float red[8];
    const int wv = tid >> 6;
    if ((tid & 63) == 0) { red[wv] = s; red[wv + 4] = sq; }
    __syncthreads();
    const float S  = red[0] + red[1] + red[2] + red[3];
    const float SQ = red[4] + red[5] + red[6] + red[7];
    const float mu = S * (1.0f / 1024.0f);
    const float var = SQ * (1.0f / 1024.0f) - mu * mu;
    const float rs = rsqrtf(var + 1e-5f);
    float4 gv = ((const float4*)g)[tid];
    float4 bv = ((const float4*)bsh)[tid];
    ushort4 o;
    o.x = f2bf((v[0] - mu) * rs * gv.x + bv.x);
    o.y = f2bf((v[1] - mu) * rs * gv.y + bv.y);
    o.z = f2bf((v[2] - mu) * rs * gv.z + bv.z);
    o.w = f2bf((v[3] - mu) * rs * gv.w + bv.w);
    ((ushort4*)out)[row * 256 + tid] = o;
}

// ---------------- 128x128 GEMM (verified structure), kept for delta --------
// EPI 2: softplus(v + bias) -> f32 out (delta, single-pass K, no split-K)
template<int EPI>
__global__ __launch_bounds__(256)
void gemm_bt(const USHORT* __restrict__ A, const USHORT* __restrict__ B,
             const float* __restrict__ bias, void* __restrict__ outp,
             void* __restrict__ outp2, int M, int N, int K, int lda, int ldb)
{
    __shared__ __align__(16) unsigned char smem[32768];
    USHORT* As = (USHORT*)smem;
    USHORT* Bs = (USHORT*)(smem + 8192);
    const int tid = threadIdx.x;
    const int lane = tid & 63;
    const int w = tid >> 6;
    const int wr = w >> 1, wc = w & 1;

    const int nx = gridDim.x, ny = gridDim.y;
    const int pid = blockIdx.y * nx + blockIdx.x;
    const int npg = 8 * nx;
    const int gid = pid / npg;
    const int first = gid * 8;
    const int rem = ny - first;
    const int gsz = (rem < 8) ? rem : 8;
    const int py = first + (pid % npg) % gsz;
    const int px = (pid % npg) / gsz;
    const int tm = py * 128;
    const int tn = px * 128;

    f32x4 acc[4][4];
    #pragma unroll
    for (int i = 0; i < 4; i++)
        #pragma unroll
        for (int j = 0; j < 4; j++) acc[i][j] = (f32x4){0.f, 0.f, 0.f, 0.f};

    const int srow = tid >> 2;
    const int scol = (tid & 3) * 8;
    const USHORT* gA0 = A + (size_t)(tm + srow) * lda + scol;
    const USHORT* gA1 = A + (size_t)(tm + 64 + srow) * lda + scol;
    const USHORT* gB0 = B + (size_t)(tn + srow) * ldb + scol;
    const USHORT* gB1 = B + (size_t)(tn + 64 + srow) * ldb + scol;
    USHORT* lA0 = As + w * 512;
    USHORT* lA1 = As + 2048 + w * 512;
    USHORT* lB0 = Bs + w * 512;
    USHORT* lB1 = Bs + 2048 + w * 512;

    const int fr = lane & 15;
    const int fko = (lane >> 4) * 8;
    const int quad = lane >> 4;

    for (int k0 = 0; k0 < K; k0 += 64) {
        gload_lds16(gA0 + k0, lA0);
        gload_lds16(gA1 + k0, lA1);
        gload_lds16(gB0 + k0, lB0);
        gload_lds16(gB1 + k0, lB1);
        gload_lds16(gA0 + k0 + 32, lA0 + 8192);
        gload_lds16(gA1 + k0 + 32, lA1 + 8192);
        gload_lds16(gB0 + k0 + 32, lB0 + 8192);
        gload_lds16(gB1 + k0 + 32, lB1 + 8192);
        __syncthreads();
        #pragma unroll
        for (int h = 0; h < 2; h++) {
            const USHORT* Ah = As + h * 8192;
            const USHORT* Bh = Bs + h * 8192;
            bf16x8 af[4], bfr[4];
            #pragma unroll
            for (int i = 0; i < 4; i++) {
                af[i]  = *(const bf16x8*)(Ah + (wr * 64 + i * 16 + fr) * 32 + fko);
                bfr[i] = *(const bf16x8*)(Bh + (wc * 64 + i * 16 + fr) * 32 + fko);
            }
            #pragma unroll
            for (int i = 0; i < 4; i++)
                #pragma unroll
                for (int j = 0; j < 4; j++)
                    acc[i][j] = __builtin_amdgcn_mfma_f32_16x16x32_bf16(af[i], bfr[j], acc[i][j], 0, 0, 0);
        }
        __syncthreads();
    }

    float* eW = (float*)(smem + (size_t)w * 4352);
    const int rr = lane >> 5;
    const int cc = lane & 31;
    const int gcolb = tn + wc * 64;
    float2 bvv = *(const float2*)&bias[gcolb + cc * 2];

    #pragma unroll
    for (int i = 0; i < 4; i++) {
        #pragma unroll
        for (int j = 0; j < 4; j++)
            #pragma unroll
            for (int r = 0; r < 4; r++)
                eW[(quad * 4 + r) * 68 + j * 16 + fr] = acc[i][j][r];
        __syncthreads();
        const int grow0 = tm + wr * 64 + i * 16;
        #pragma unroll
        for (int rp = 0; rp < 8; rp++) {
            const int row = rp * 2 + rr;
            const float2 v = *(const float2*)&eW[row * 68 + cc * 2];
            const size_t gidx = (size_t)(grow0 + row) * N + gcolb + cc * 2;
            if constexpr (EPI == 2) {
                const float z0 = v.x + bvv.x, z1 = v.y + bvv.y;
                const float o0 = (z0 > 20.f) ? z0 : 0.69314718f * __log2f(1.f + fexp2(z0 * 1.44269504f));
                const float o1 = (z1 > 20.f) ? z1 : 0.69314718f * __log2f(1.f + fexp2(z1 * 1.44269504f));
                *(float2*)((float*)outp + gidx) = make_float2(o0, o1);
            }
        }
        __syncthreads();
    }
    (void)outp2; (void)M;
}

// ---------------- 256x256 GEMM, 8 waves, BK=32, ring-4 LDS pipeline ---------
// T3/T4: stage 2 K-tiles ahead into a 4-slot LDS ring (4x32KB = 128KB);
//   counted s_waitcnt vmcnt(4) at each tile boundary (vmcnt(0) only on the
//   last tile); ONE raw s_barrier per K-tile -> 32 MFMA per barrier, global
//   loads stay in flight across barriers.
// T2: k-unit XOR swizzle u ^= (row>>1)&3, applied on the global SOURCE addr
//   (global_load_lds writes LDS linearly) and on the ds_read_b128 address ->
//   conflict-free b128 reads (per-8-lane beat covers distinct bank quads).
// T5: setprio(1) around each 16-MFMA cluster.  T1: bijective XCD pid swizzle.
// Per wave: 128x64 output = f32x4 acc[8][4].  No __syncthreads anywhere.
// EPI 1: gelu(v+bias) -> bf16.  EPI 3: raw bf16 partial, split-K via z.
template<int EPI>
__global__ __launch_bounds__(512)
void gemm256(const USHORT* __restrict__ A, const USHORT* __restrict__ B,
             const float* __restrict__ bias, void* __restrict__ outp,
             void* __restrict__ outp2, int M, int N, int K, int lda, int ldb)
{
    __shared__ __align__(16) unsigned char smem[131072];
    const int tid = threadIdx.x;
    const int lane = tid & 63;
    const int w = tid >> 6;          // 0..7
    const int wr = w >> 2;           // 0..1  (row half)
    const int wc = w & 3;            // 0..3  (col quarter)

    // T1: XCD-bijective swizzle (both grids have nwg % 8 == 0)
    const int gx = gridDim.x;
    const int pid = blockIdx.y * gx + blockIdx.x;
    const int nwg = gx * gridDim.y;
    const int cpx = nwg >> 3;
    const int s = (pid & 7) * cpx + (pid >> 3);
    const int px = s % gx;
    const int py = s / gx;
    const int tm = py * 256;
    const int tn = px * 256;

    USHORT* po = nullptr;
    if constexpr (EPI == 3) {
        const int z = blockIdx.z;
        A += (size_t)z * K;          // K-slice within row (lda = full K)
        B += (size_t)z * K;
        po = ((z < 2) ? (USHORT*)outp : (USHORT*)outp2) + (size_t)(z & 1) * ((size_t)M * N);
    }

    // staging: LDS 16B-unit P = round*512 + tid -> row r=P>>2, unit u=P&3.
    // source fetches unit (u ^ ((r>>1)&3)) so linear LDS holds swizzled data.
    const int sr = tid >> 2;                         // row, round 0 (+128 rnd 1)
    const int su = (tid & 3) ^ ((tid >> 3) & 3);     // pre-swizzled k-unit
    const USHORT* gA0 = A + (size_t)(tm + sr) * lda + su * 8;
    const USHORT* gA1 = A + (size_t)(tm + 128 + sr) * lda + su * 8;
    const USHORT* gB0 = B + (size_t)(tn + sr) * ldb + su * 8;
    const USHORT* gB1 = B + (size_t)(tn + 128 + sr) * ldb + su * 8;

    // fragment read offset (USHORT units): row fr, k-unit (quad ^ ((fr>>1)&3))
    const int fr = lane & 15;
    const int quad = lane >> 4;
    const int uR = quad ^ ((fr >> 1) & 3);
    const int loff = fr * 32 + uR * 8;

    f32x4 acc[8][4];
    #pragma unroll
    for (int i = 0; i < 8; i++)
        #pragma unroll
        for (int j = 0; j < 4; j++) acc[i][j] = (f32x4){0.f, 0.f, 0.f, 0.f};

    const int NT = K >> 5;           // BK=32

    auto stage = [&](int t) {        // 4 x 16B loads/thread = 32KB/tile/block
        unsigned char* sb = smem + (size_t)(t & 3) * 32768;
        const size_t koff = (size_t)t * 32;
        gload_lds16(gA0 + koff, sb + w * 1024);            // A rows 0..127
        gload_lds16(gA1 + koff, sb + 8192 + w * 1024);     // A rows 128..255
        gload_lds16(gB0 + koff, sb + 16384 + w * 1024);    // B rows 0..127
        gload_lds16(gB1 + koff, sb + 24576 + w * 1024);    // B rows 128..255
    };

    stage(0);
    stage(1);

    for (int t = 0; t < NT; ++t) {
        // tile t's 4 loads retired; tile t+1's may stay in flight (T4)
        if (t + 1 < NT) asm volatile("s_waitcnt vmcnt(4)" ::: "memory");
        else            asm volatile("s_waitcnt vmcnt(0)" ::: "memory");
        __builtin_amdgcn_s_barrier();
        if (t + 2 < NT) stage(t + 2);          // slot (t+2)&3: 2-barrier dist

        const USHORT* sA = (const USHORT*)(smem + (size_t)(t & 3) * 32768);
        const USHORT* sB = sA + 8192;          // +16KB
        bf16x8 a[4], b[4];
        #pragma unroll
        for (int j = 0; j < 4; j++)
            b[j] = *(const bf16x8*)(sB + (wc * 64 + j * 16) * 32 + loff);
        #pragma unroll
        for (int i = 0; i < 4; i++)
            a[i] = *(const bf16x8*)(sA + (wr * 128 + i * 16) * 32 + loff);
        __builtin_amdgcn_s_setprio(1);
        #pragma unroll
        for (int i = 0; i < 4; i++)
            #pragma unroll
            for (int j = 0; j < 4; j++)
                acc[i][j] = __builtin_amdgcn_mfma_f32_16x16x32_bf16(a[i], b[j], acc[i][j], 0, 0, 0);
        __builtin_amdgcn_s_setprio(0);
        #pragma unroll
        for (int i = 0; i < 4; i++)
            a[i] = *(const bf16x8*)(sA + (wr * 128 + 64 + i * 16) * 32 + loff);
        __builtin_amdgcn_s_setprio(1);
        #pragma unroll
        for (int i = 0; i < 4; i++)
            #pragma unroll
            for (int j = 0; j < 4; j++)
                acc[4 + i][j] = __builtin_amdgcn_mfma_f32_16x16x32_bf16(a[i], b[j], acc[4 + i][j], 0, 0, 0);
        __builtin_amdgcn_s_setprio(0);
    }

    // epilogue: per-wave private 16x68 f32 LDS slice (bytes [0,34816) =
    // slots 0/1 region; last tile read slot 3 -> no cross-wave hazard, and
    // each wave only touches its own slice -> no barrier needed at all.
    float* eW = (float*)(smem + (size_t)w * 4352);
    const int erow = lane >> 2;          // 0..15
    const int ecq = lane & 3;            // 16-col quarter
    const int gcolb = tn + wc * 64 + ecq * 16;
    float bb[16];
    if constexpr (EPI == 1) {
        #pragma unroll
        for (int q = 0; q < 4; q++) {
            float4 bv = *(const float4*)&bias[gcolb + q * 4];
            bb[q*4+0] = bv.x; bb[q*4+1] = bv.y; bb[q*4+2] = bv.z; bb[q*4+3] = bv.w;
        }
    }
    #pragma unroll
    for (int i = 0; i < 8; i++) {
        #pragma unroll
        for (int j = 0; j < 4; j++)
            #pragma unroll
            for (int r = 0; r < 4; r++)
                eW[(quad * 4 + r) * 68 + j * 16 + fr] = acc[i][j][r];
        float v[16];
        #pragma unroll
        for (int q = 0; q < 4; q++) {
            float4 t4 = *(const float4*)&eW[erow * 68 + ecq * 16 + q * 4];
            v[q*4+0] = t4.x; v[q*4+1] = t4.y; v[q*4+2] = t4.z; v[q*4+3] = t4.w;
        }
        const int grow = tm + wr * 128 + i * 16 + erow;
        uint32_t pk[8];
        if constexpr (EPI == 1) {
            #pragma unroll
            for (int q = 0; q < 8; q++) {
                const float z0 = v[2*q]   + bb[2*q];
                const float z1 = v[2*q+1] + bb[2*q+1];
                const float u0 = z0 * (0.7978845608f + 0.035677408f * z0 * z0);
                const float u1 = z1 * (0.7978845608f + 0.035677408f * z1 * z1);
                const float s0 = __builtin_amdgcn_rcpf(1.f + fexp2(2.885390082f * u0));
                const float s1 = __builtin_amdgcn_rcpf(1.f + fexp2(2.885390082f * u1));
                const float g0 = z0 * (1.f - s0), g1 = z1 * (1.f - s1);
                pk[q] = (uint32_t)f2bf(g0) | ((uint32_t)f2bf(g1) << 16);
            }
            USHORT* op = (USHORT*)outp + (size_t)grow * N + gcolb;
            *(uint4*)op = make_uint4(pk[0], pk[1], pk[2], pk[3]);
            *(uint4*)(op + 8) = make_uint4(pk[4], pk[5], pk[6], pk[7]);
        } else {
            #pragma unroll
            for (int q = 0; q < 8; q++)
                pk[q] = (uint32_t)f2bf(v[2*q]) | ((uint32_t)f2bf(v[2*q+1]) << 16);
            USHORT* op = po + (size_t)grow * N + gcolb;
            *(uint4*)op = make_uint4(pk[0], pk[1], pk[2], pk[3]);
            *(uint4*)(op + 8) = make_uint4(pk[4], pk[5], pk[6], pk[7]);
        }
    }
}

// ---------------- FFN2 split-K reduce: out = sum(partials) + bias + extra ---
__global__ __launch_bounds__(256)
void ffn2_reduce(const USHORT* __restrict__ p01, const USHORT* __restrict__ p23,
                 const float* __restrict__ bias, const float* __restrict__ extra,
                 float* __restrict__ out)
{
    const size_t PS = (size_t)4096 * 1024;
    const size_t i = ((size_t)blockIdx.x * 256 + threadIdx.x) * 4;
    ushort4 a = *(const ushort4*)(p01 + i);
    ushort4 b = *(const ushort4*)(p01 + PS + i);
    ushort4 c = *(const ushort4*)(p23 + i);
    ushort4 d = *(const ushort4*)(p23 + PS + i);
    float4 bv = *(const float4*)(bias + (i & 1023));
    float4 ev = *(const float4*)(extra + i);
    float4 o;
    o.x = b2f(a.x) + b2f(b.x) + b2f(c.x) + b2f(d.x) + bv.x + ev.x;
    o.y = b2f(a.y) + b2f(b.y) + b2f(c.y) + b2f(d.y) + bv.y + ev.y;
    o.z = b2f(a.z) + b2f(b.z) + b2f(c.z) + b2f(d.z) + bv.z + ev.z;
    o.w = b2f(a.w) + b2f(b.w) + b2f(c.w) + b2f(d.w) + bv.w + ev.w;
    *(float4*)(out + i) = o;
}

// ---------------- bc = xn @ Wbc^T + bbc via MFMA: 64 tokens/block ----------
__global__ __launch_bounds__(256)
void bc_mfma(const USHORT* __restrict__ xn, const USHORT* __restrict__ WbcB,
             const float* __restrict__ bbc, float* __restrict__ bc)
{
    __shared__ __align__(16) USHORT As[64 * 32];
    __shared__ __align__(16) USHORT Bs[32 * 32];
    const int tid = threadIdx.x;
    const int lane = tid & 63;
    const int w = tid >> 6;
    const int tok0 = blockIdx.x * 64;

    const int srow = tid >> 2;
    const int scol = (tid & 3) * 8;
    const USHORT* gA = xn + (size_t)(tok0 + srow) * 1024 + scol;
    const USHORT* gB = WbcB + (size_t)srow * 1024 + scol;
    USHORT* lA = As + w * 512;
    USHORT* lB = Bs + w * 512;

    const int fr = lane & 15;
    const int fko = (lane >> 4) * 8;
    const int quad = lane >> 4;

    f32x4 acc[2];
    acc[0] = (f32x4){0.f, 0.f, 0.f, 0.f};
    acc[1] = (f32x4){0.f, 0.f, 0.f, 0.f};

    for (int k0 = 0; k0 < 1024; k0 += 32) {
        gload_lds16(gA + k0, lA);
        if (w < 2) gload_lds16(gB + k0, lB);
        __syncthreads();
        bf16x8 af = *(const bf16x8*)(As + (w * 16 + fr) * 32 + fko);
        bf16x8 b0 = *(const bf16x8*)(Bs + (fr) * 32 + fko);
        bf16x8 b1 = *(const bf16x8*)(Bs + (16 + fr) * 32 + fko);
        acc[0] = __builtin_amdgcn_mfma_f32_16x16x32_bf16(af, b0, acc[0], 0, 0, 0);
        acc[1] = __builtin_amdgcn_mfma_f32_16x16x32_bf16(af, b1, acc[1], 0, 0, 0);
        __syncthreads();
    }

    #pragma unroll
    for (int j = 0; j < 2; j++) {
        const int col = j * 16 + fr;
        const float bv = bbc[col];
        #pragma unroll
        for (int r = 0; r < 4; r++) {
            const int row = tok0 + w * 16 + quad * 4 + r;
            bc[(size_t)row * 32 + col] = acc[j][r] + bv;
        }
    }
}

// ---------------- selective scan v3: chunked parallel, lane=h, n in regs ----
#define SCAN_P 64
#define SCAN_T 32

__global__ __launch_bounds__(256)
void scan_pass1(const USHORT* __restrict__ xn, const float* __restrict__ delta,
                const float* __restrict__ bc, const float* __restrict__ Alog,
                float* __restrict__ sEnd, float* __restrict__ Ptot)
{
    const int tid = threadIdx.x;
    const int h = blockIdx.x * 256 + tid;
    const int b = blockIdx.y;
    const int p = blockIdx.z;
    const size_t tok0 = (size_t)b * 2048 + p * SCAN_T;

    __shared__ __align__(16) float sBC[SCAN_T][32];
    {
        int t = tid >> 3, q = (tid & 7) * 4;
        *(float4*)&sBC[t][q] = *(const float4*)(bc + (tok0 + t) * 32 + q);
    }

    float en[16], s[16], P[16];
    #pragma unroll
    for (int k = 0; k < 4; k++) {
        float4 a = *(const float4*)(Alog + h * 16 + k * 4);
        en[k*4+0] = -__expf(a.x) * 1.44269504f;
        en[k*4+1] = -__expf(a.y) * 1.44269504f;
        en[k*4+2] = -__expf(a.z) * 1.44269504f;
        en[k*4+3] = -__expf(a.w) * 1.44269504f;
    }
    #pragma unroll
    for (int n = 0; n < 16; n++) { s[n] = 0.f; P[n] = 1.f; }
    __syncthreads();

    const float* dp = delta + tok0 * 1024 + h;
    const USHORT* xp = xn + tok0 * 1024 + h;
    float d_c = dp[0];
    USHORT x_c = xp[0];
    for (int t = 0; t < SCAN_T; ++t) {
        const int tn = (t < SCAN_T - 1) ? t + 1 : t;
        float d_n = dp[(size_t)tn * 1024];
        USHORT x_n = xp[(size_t)tn * 1024];
        const float dx = d_c * b2f(x_c);
        #pragma unroll
        for (int k = 0; k < 4; k++) {
            float4 Bv = *(const float4*)&sBC[t][k*4];
            float bb[4] = { Bv.x, Bv.y, Bv.z, Bv.w };
            #pragma unroll
            for (int j = 0; j < 4; j++) {
                const int n = k*4 + j;
                const float dA = fexp2(d_c * en[n]);
                s[n] = fmaf(dA, s[n], dx * bb[j]);
                P[n] *= dA;
            }
        }
        d_c = d_n; x_c = x_n;
    }

    const size_t off = (size_t)p * 32768 + ((size_t)b * 1024 + h) * 16;
    #pragma unroll
    for (int k = 0; k < 4; k++) {
        *(float4*)(sEnd + off + k*4) = (float4){ s[k*4], s[k*4+1], s[k*4+2], s[k*4+3] };
        *(float4*)(Ptot + off + k*4) = (float4){ P[k*4], P[k*4+1], P[k*4+2], P[k*4+3] };
    }
}

__global__ __launch_bounds__(256)
void scan_mid(const float* __restrict__ sEnd, const float* __restrict__ Ptot,
              float* __restrict__ sIn)
{
    const int L = blockIdx.x * 256 + threadIdx.x;
    float s = 0.f;
    #pragma unroll 8
    for (int p = 0; p < SCAN_P; ++p) {
        const size_t off = (size_t)p * 32768 + L;
        sIn[off] = s;
        s = fmaf(Ptot[off], s, sEnd[off]);
    }
}

__global__ __launch_bounds__(256)
void scan_pass2(const float* __restrict__ x, const USHORT* __restrict__ xn,
                const float* __restrict__ delta, const float* __restrict__ bc,
                const float* __restrict__ Alog, const float* __restrict__ Dp,
                const float* __restrict__ sIn, float* __restrict__ ssm)
{
    const int tid = threadIdx.x;
    const int h = blockIdx.x * 256 + tid;
    const int b = blockIdx.y;
    const int p = blockIdx.z;
    const size_t tok0 = (size_t)b * 2048 + p * SCAN_T;

    __shared__ __align__(16) float sBC[SCAN_T][32];
    {
        int t = tid >> 3, q = (tid & 7) * 4;
        *(float4*)&sBC[t][q] = *(const float4*)(bc + (tok0 + t) * 32 + q);
    }

    float en[16], s[16];
    #pragma unroll
    for (int k = 0; k < 4; k++) {
        float4 a = *(const float4*)(Alog + h * 16 + k * 4);
        en[k*4+0] = -__expf(a.x) * 1.44269504f;
        en[k*4+1] = -__expf(a.y) * 1.44269504f;
        en[k*4+2] = -__expf(a.z) * 1.44269504f;
        en[k*4+3] = -__expf(a.w) * 1.44269504f;
    }
    const size_t off = (size_t)p * 32768 + ((size_t)b * 1024 + h) * 16;
    #pragma unroll
    for (int k = 0; k < 4; k++) {
        float4 v = *(const float4*)(sIn + off + k*4);
        s[k*4] = v.x; s[k*4+1] = v.y; s[k*4+2] = v.z; s[k*4+3] = v.w;
    }
    const float Dv = Dp[h];
    __syncthreads();

    const float* dp = delta + tok0 * 1024 + h;
    const USHORT* xp = xn + tok0 * 1024 + h;
    const float* xrp = x + tok0 * 1024 + h;
    float* op = ssm + tok0 * 1024 + h;

    float d_c = dp[0];
    USHORT x_c = xp[0];
    float xr_c = xrp[0];
    for (int t = 0; t < SCAN_T; ++t) {
        const int tn = (t < SCAN_T - 1) ? t + 1 : t;
        float d_n = dp[(size_t)tn * 1024];
        USHORT x_n = xp[(size_t)tn * 1024];
        float xr_n = xrp[(size_t)tn * 1024];
        const float xv = b2f(x_c);
        const float dx = d_c * xv;
        float y = 0.f;
        #pragma unroll
        for (int k = 0; k < 4; k++) {
            float4 Bv = *(const float4*)&sBC[t][k*4];
            float4 Cv = *(const float4*)&sBC[t][16 + k*4];
            float bb[4] = { Bv.x, Bv.y, Bv.z, Bv.w };
            float cc[4] = { Cv.x, Cv.y, Cv.z, Cv.w };
            #pragma unroll
            for (int j = 0; j < 4; j++) {
                const int n = k*4 + j;
                const float dA = fexp2(d_c * en[n]);
                s[n] = fmaf(dA, s[n], dx * bb[j]);
                y = fmaf(cc[j], s[n], y);
            }
        }
        op[(size_t)t * 1024] = xr_c + y + Dv * xv;
        d_c = d_n; x_c = x_n; xr_c = xr_n;
    }
}

extern "C" void kernel_launch(void* const* d_in, const int* in_sizes, int n_in,
                              void* d_out, int out_size, void* d_ws, size_t ws_size,
                              hipStream_t stream)
{
    const float* x    = (const float*)d_in[0];
    const float* ln1g = (const float*)d_in[1];
    const float* ln1b = (const float*)d_in[2];
    const float* Wd   = (const float*)d_in[3];
    const float* bd   = (const float*)d_in[4];
    const float* Wbc  = (const float*)d_in[5];
    const float* bbc  = (const float*)d_in[6];
    const float* Alog = (const float*)d_in[7];
    const float* Dp   = (const float*)d_in[8];
    const float* ln2g = (const float*)d_in[9];
    const float* ln2b = (const float*)d_in[10];
    const float* W1   = (const float*)d_in[11];
    const float* b1   = (const float*)d_in[12];
    const float* W2   = (const float*)d_in[13];
    const float* b2   = (const float*)d_in[14];
    float* out = (float*)d_out;

    char* ws = (char*)d_ws;
    const size_t MB = 1024 * 1024;
    float*  deltaW = (float*)(ws + 0);            // 16 MiB (4096x1024 f32)
    float*  ssmW   = (float*)(ws + 16 * MB);      // 16 MiB (4096x1024 f32)
    USHORT* xnW    = (USHORT*)(ws + 32 * MB);     //  8 MiB (4096x1024 bf16)
    USHORT* nrmW   = (USHORT*)(ws + 40 * MB);     //  8 MiB (4096x1024 bf16)
    USHORT* hffW   = (USHORT*)(ws + 48 * MB);     // 32 MiB (4096x4096 bf16)
    float*  bcW    = (float*)(ws + 80 * MB);      // 512 KiB (4096x32 f32)
    USHORT* WdB    = (USHORT*)(ws + 81 * MB);     //  2 MiB (1024x1024 bf16)
    USHORT* W1B    = (USHORT*)(ws + 83 * MB);     //  8 MiB (4096x1024 bf16)
    USHORT* W2B    = (USHORT*)(ws + 91 * MB);     //  8 MiB (1024x4096 bf16)
    USHORT* WbcB   = (USHORT*)(ws + 99 * MB);     // 64 KiB (32x1024 bf16)
    // scan scratch aliases hffW (dead until FFN1): 3 x 8 MiB
    float*  sEndW  = (float*)(ws + 48 * MB);
    float*  PtotW  = (float*)(ws + 56 * MB);
    float*  sInW   = (float*)(ws + 64 * MB);
    // FFN2 split-K partials alias deltaW (splits 0,1) and xnW/nrmW (2,3)
    USHORT* ffn2p01 = (USHORT*)(ws + 0);          // 16 MiB: 2 x 4096x1024 bf16
    USHORT* ffn2p23 = (USHORT*)(ws + 32 * MB);    // 16 MiB: 2 x 4096x1024 bf16

    // 0. convert weights f32 -> bf16
    f2b_kernel<<<1024, 256, 0, stream>>>(Wd, WdB, 1024 * 1024);
    f2b_kernel<<<4096, 256, 0, stream>>>(W1, W1B, 4096 * 1024);
    f2b_kernel<<<4096, 256, 0, stream>>>(W2, W2B, 1024 * 4096);
    f2b_kernel<<<32, 256, 0, stream>>>(Wbc, WbcB, 32 * 1024);
    // 1. xn = LN1(x)                         (bf16)
    ln_kernel<<<4096, 256, 0, stream>>>(x, ln1g, ln1b, xnW);
    // 2. delta = softplus(xn @ Wd^T + bd)    (f32), fused epilogue, no split-K
    gemm_bt<2><<<dim3(8, 32), 256, 0, stream>>>(xnW, WdB, bd, deltaW, nullptr, 4096, 1024, 1024, 1024, 1024);
    // 3. bc = xn @ Wbc^T + bbc               (f32), MFMA micro-GEMM
    bc_mfma<<<64, 256, 0, stream>>>(xnW, WbcB, bbc, bcW);
    // 4. ssm_out = x + scan(...) + D*xn      (f32), chunked parallel scan
    scan_pass1<<<dim3(4, 2, SCAN_P), 256, 0, stream>>>(xnW, deltaW, bcW, Alog, sEndW, PtotW);
    scan_mid<<<128, 256, 0, stream>>>(sEndW, PtotW, sInW);
    scan_pass2<<<dim3(4, 2, SCAN_P), 256, 0, stream>>>(x, xnW, deltaW, bcW, Alog, Dp, sInW, ssmW);
    // 5. normed = LN2(ssm_out)               (bf16)
    ln_kernel<<<4096, 256, 0, stream>>>(ssmW, ln2g, ln2b, nrmW);
    // 6. hff = gelu(normed @ W1^T + b1)      (bf16), 256^2 pipelined GEMM
    gemm256<1><<<dim3(16, 16), 512, 0, stream>>>(nrmW, W1B, b1, hffW, nullptr, 4096, 4096, 1024, 1024, 1024);
    // 7a. FFN2 split-K=4 partial GEMMs       (bf16 partials, grid.z = split)
    gemm256<3><<<dim3(4, 16, 4), 512, 0, stream>>>(hffW, W2B, nullptr, ffn2p01, ffn2p23, 4096, 1024, 1024, 4096, 4096);
    // 7b. out = sum(partials) + b2 + ssm_out (f32)
    ffn2_reduce<<<4096, 256, 0, stream>>>(ffn2p01, ffn2p23, b2, ssmW, out);

    (void)in_sizes; (void)n_in; (void)out_size; (void)ws_size;
}

// Round 2
// 304.211 us; speedup vs baseline: 1.0782x; 1.0069x over previous
//
#include <hip/hip_runtime.h>
#include <cstdint>
#include <cstddef>

typedef unsigned short USHORT;
typedef __bf16 bf16x8 __attribute__((ext_vector_type(8)));
typedef float f32x4 __attribute__((ext_vector_type(4)));

__device__ __forceinline__ float b2f(USHORT u) {
    union { unsigned int i; float f; } v; v.i = ((unsigned int)u) << 16; return v.f;
}
__device__ __forceinline__ USHORT f2bf(float f) {
    union { float f; unsigned int i; } v; v.f = f;
    unsigned int u = v.i;
    unsigned int r = (u + 0x7FFFu + ((u >> 16) & 1u)) >> 16;
    return (USHORT)r;
}
__device__ __forceinline__ float fexp2(float x) { return __builtin_amdgcn_exp2f(x); }

__device__ __forceinline__ void gload_lds16(const void* g, void* l) {
    __builtin_amdgcn_global_load_lds(
        (const __attribute__((address_space(1))) void*)(uintptr_t)g,
        (__attribute__((address_space(3))) void*)(uint32_t)(uintptr_t)l,
        16, 0, 0);
}

// ---------------- f32 -> bf16 conversion (weights), 4 elems/thread ----------
__global__ __launch_bounds__(256)
void f2b_kernel(const float* __restrict__ src, USHORT* __restrict__ dst, int n)
{
    int i = (blockIdx.x * 256 + threadIdx.x) * 4;
    if (i < n) {
        float4 v = *(const float4*)(src + i);
        ushort4 o;
        o.x = f2bf(v.x); o.y = f2bf(v.y); o.z = f2bf(v.z); o.w = f2bf(v.w);
        *(ushort4*)(dst + i) = o;
    }
}

// ---------------- LayerNorm: f32 in -> bf16 out. 1 block/token, 256 thr ----
__global__ __launch_bounds__(256)
void ln_kernel(const float* __restrict__ inp, const float* __restrict__ g,
               const float* __restrict__ bsh, USHORT* __restrict__ out)
{
    const int tid = threadIdx.x;
    const size_t row = blockIdx.x;
    float4 t = ((const float4*)inp)[row * 256 + tid];
    float v[4] = { t.x, t.y, t.z, t.w };
    float s = v[0] + v[1] + v[2] + v[3];
    float sq = v[0]*v[0] + v[1]*v[1] + v[2]*v[2] + v[3]*v[3];
    #pragma unroll
    for (int off = 32; off; off >>= 1) { s += __shfl_down(s, off); sq += __shfl_down(sq, off); }
    __shared__ float red[8];
    const int wv = tid >> 6;
    if ((tid & 63) == 0) { red[wv] = s; red[wv + 4] = sq; }
    __syncthreads();
    const float S  = red[0] + red[1] + red[2] + red[3];
    const float SQ = red[4] + red[5] + red[6] + red[7];
    const float mu = S * (1.0f / 1024.0f);
    const float var = SQ * (1.0f / 1024.0f) - mu * mu;
    const float rs = rsqrtf(var + 1e-5f);
    float4 gv = ((const float4*)g)[tid];
    float4 bv = ((const float4*)bsh)[tid];
    ushort4 o;
    o.x = f2bf((v[0] - mu) * rs * gv.x + bv.x);
    o.y = f2bf((v[1] - mu) * rs * gv.y + bv.y);
    o.z = f2bf((v[2] - mu) * rs * gv.z + bv.z);
    o.w = f2bf((v[3] - mu) * rs * gv.w + bv.w);
    ((ushort4*)out)[row * 256 + tid] = o;
}

// ---------------- 128x128 GEMM (verified structure), kept for delta --------
// EPI 2: softplus(v + bias) -> f32 out (delta, single-pass K, no split-K)
template<int EPI>
__global__ __launch_bounds__(256)
void gemm_bt(const USHORT* __restrict__ A, const USHORT* __restrict__ B,
             const float* __restrict__ bias, void* __restrict__ outp,
             void* __restrict__ outp2, int M, int N, int K, int lda, int ldb)
{
    __shared__ __align__(16) unsigned char smem[32768];
    USHORT* As = (USHORT*)smem;
    USHORT* Bs = (USHORT*)(smem + 8192);
    const int tid = threadIdx.x;
    const int lane = tid & 63;
    const int w = tid >> 6;
    const int wr = w >> 1, wc = w & 1;

    const int nx = gridDim.x, ny = gridDim.y;
    const int pid = blockIdx.y * nx + blockIdx.x;
    const int npg = 8 * nx;
    const int gid = pid / npg;
    const int first = gid * 8;
    const int rem = ny - first;
    const int gsz = (rem < 8) ? rem : 8;
    const int py = first + (pid % npg) % gsz;
    const int px = (pid % npg) / gsz;
    const int tm = py * 128;
    const int tn = px * 128;

    f32x4 acc[4][4];
    #pragma unroll
    for (int i = 0; i < 4; i++)
        #pragma unroll
        for (int j = 0; j < 4; j++) acc[i][j] = (f32x4){0.f, 0.f, 0.f, 0.f};

    const int srow = tid >> 2;
    const int scol = (tid & 3) * 8;
    const USHORT* gA0 = A + (size_t)(tm + srow) * lda + scol;
    const USHORT* gA1 = A + (size_t)(tm + 64 + srow) * lda + scol;
    const USHORT* gB0 = B + (size_t)(tn + srow) * ldb + scol;
    const USHORT* gB1 = B + (size_t)(tn + 64 + srow) * ldb + scol;
    USHORT* lA0 = As + w * 512;
    USHORT* lA1 = As + 2048 + w * 512;
    USHORT* lB0 = Bs + w * 512;
    USHORT* lB1 = Bs + 2048 + w * 512;

    const int fr = lane & 15;
    const int fko = (lane >> 4) * 8;
    const int quad = lane >> 4;

    for (int k0 = 0; k0 < K; k0 += 64) {
        gload_lds16(gA0 + k0, lA0);
        gload_lds16(gA1 + k0, lA1);
        gload_lds16(gB0 + k0, lB0);
        gload_lds16(gB1 + k0, lB1);
        gload_lds16(gA0 + k0 + 32, lA0 + 8192);
        gload_lds16(gA1 + k0 + 32, lA1 + 8192);
        gload_lds16(gB0 + k0 + 32, lB0 + 8192);
        gload_lds16(gB1 + k0 + 32, lB1 + 8192);
        __syncthreads();
        #pragma unroll
        for (int h = 0; h < 2; h++) {
            const USHORT* Ah = As + h * 8192;
            const USHORT* Bh = Bs + h * 8192;
            bf16x8 af[4], bfr[4];
            #pragma unroll
            for (int i = 0; i < 4; i++) {
                af[i]  = *(const bf16x8*)(Ah + (wr * 64 + i * 16 + fr) * 32 + fko);
                bfr[i] = *(const bf16x8*)(Bh + (wc * 64 + i * 16 + fr) * 32 + fko);
            }
            #pragma unroll
            for (int i = 0; i < 4; i++)
                #pragma unroll
                for (int j = 0; j < 4; j++)
                    acc[i][j] = __builtin_amdgcn_mfma_f32_16x16x32_bf16(af[i], bfr[j], acc[i][j], 0, 0, 0);
        }
        __syncthreads();
    }

    float* eW = (float*)(smem + (size_t)w * 4352);
    const int rr = lane >> 5;
    const int cc = lane & 31;
    const int gcolb = tn + wc * 64;
    float2 bvv = *(const float2*)&bias[gcolb + cc * 2];

    #pragma unroll
    for (int i = 0; i < 4; i++) {
        #pragma unroll
        for (int j = 0; j < 4; j++)
            #pragma unroll
            for (int r = 0; r < 4; r++)
                eW[(quad * 4 + r) * 68 + j * 16 + fr] = acc[i][j][r];
        __syncthreads();
        const int grow0 = tm + wr * 64 + i * 16;
        #pragma unroll
        for (int rp = 0; rp < 8; rp++) {
            const int row = rp * 2 + rr;
            const float2 v = *(const float2*)&eW[row * 68 + cc * 2];
            const size_t gidx = (size_t)(grow0 + row) * N + gcolb + cc * 2;
            if constexpr (EPI == 2) {
                const float z0 = v.x + bvv.x, z1 = v.y + bvv.y;
                const float o0 = (z0 > 20.f) ? z0 : 0.69314718f * __log2f(1.f + fexp2(z0 * 1.44269504f));
                const float o1 = (z1 > 20.f) ? z1 : 0.69314718f * __log2f(1.f + fexp2(z1 * 1.44269504f));
                *(float2*)((float*)outp + gidx) = make_float2(o0, o1);
            }
        }
        __syncthreads();
    }
    (void)outp2; (void)M;
}

// ---------------- 256x256 GEMM, 8 waves, BK=32, ring-4, 2-phase interleave --
// T3/T4: ring-4 LDS (4x32KB), stage 2 tiles ahead, vmcnt(4) at boundary only.
// Per K-tile: TWO phases of 16 MFMA.  Phase ordering (m201 pattern):
//   [reads for phase p | 2 gloads] -> s_barrier -> setprio(1) 16xMFMA setprio(0)
// so phase p+1's ds_reads + gloads issue while other waves still run phase
// p's MFMA; the boundary vmcnt(4)+barrier is the trailing fence of phase 1.
// Phase barriers are scheduling-only; ALL correctness hazards are guarded by
// the boundary vmcnt+barrier (unchanged, verified in R1).
// T2: k-unit XOR swizzle (pre-swizzled global source + swizzled ds_read) --
//   zero bank conflicts measured.  T5 setprio.  T1 bijective XCD swizzle.
template<int EPI>
__global__ __launch_bounds__(512)
void gemm256(const USHORT* __restrict__ A, const USHORT* __restrict__ B,
             const float* __restrict__ bias, void* __restrict__ outp,
             void* __restrict__ outp2, int M, int N, int K, int lda, int ldb)
{
    __shared__ __align__(16) unsigned char smem[131072];
    const int tid = threadIdx.x;
    const int lane = tid & 63;
    const int w = tid >> 6;          // 0..7
    const int wr = w >> 2;           // 0..1  (row half)
    const int wc = w & 3;            // 0..3  (col quarter)

    // T1: XCD-bijective swizzle (both grids have nwg % 8 == 0)
    const int gx = gridDim.x;
    const int pid = blockIdx.y * gx + blockIdx.x;
    const int nwg = gx * gridDim.y;
    const int cpx = nwg >> 3;
    const int s = (pid & 7) * cpx + (pid >> 3);
    const int px = s % gx;
    const int py = s / gx;
    const int tm = py * 256;
    const int tn = px * 256;

    USHORT* po = nullptr;
    if constexpr (EPI == 3) {
        const int z = blockIdx.z;
        A += (size_t)z * K;          // K-slice within row (lda = full K)
        B += (size_t)z * K;
        po = ((z < 2) ? (USHORT*)outp : (USHORT*)outp2) + (size_t)(z & 1) * ((size_t)M * N);
    }

    // staging: LDS 16B-unit P = round*512 + tid -> row r=P>>2, unit u=P&3.
    // source fetches unit (u ^ ((r>>1)&3)) so linear LDS holds swizzled data.
    const int sr = tid >> 2;                         // row, round 0 (+128 rnd 1)
    const int su = (tid & 3) ^ ((tid >> 3) & 3);     // pre-swizzled k-unit
    const USHORT* gA0 = A + (size_t)(tm + sr) * lda + su * 8;
    const USHORT* gA1 = A + (size_t)(tm + 128 + sr) * lda + su * 8;
    const USHORT* gB0 = B + (size_t)(tn + sr) * ldb + su * 8;
    const USHORT* gB1 = B + (size_t)(tn + 128 + sr) * ldb + su * 8;

    // fragment read offset (USHORT units): row fr, k-unit (quad ^ ((fr>>1)&3))
    const int fr = lane & 15;
    const int quad = lane >> 4;
    const int uR = quad ^ ((fr >> 1) & 3);
    const int loff = fr * 32 + uR * 8;

    f32x4 acc[8][4];
    #pragma unroll
    for (int i = 0; i < 8; i++)
        #pragma unroll
        for (int j = 0; j < 4; j++) acc[i][j] = (f32x4){0.f, 0.f, 0.f, 0.f};

    const int NT = K >> 5;           // BK=32

    auto stageAll = [&](int t) {     // prologue only
        unsigned char* sb = smem + (size_t)(t & 3) * 32768;
        const size_t koff = (size_t)t * 32;
        gload_lds16(gA0 + koff, sb + w * 1024);
        gload_lds16(gA1 + koff, sb + 8192 + w * 1024);
        gload_lds16(gB0 + koff, sb + 16384 + w * 1024);
        gload_lds16(gB1 + koff, sb + 24576 + w * 1024);
    };

    stageAll(0);
    stageAll(1);

    for (int t = 0; t < NT; ++t) {
        // boundary: tile t's loads retired; tile t+1's 4 may stay in flight
        if (t + 1 < NT) asm volatile("s_waitcnt vmcnt(4)" ::: "memory");
        else            asm volatile("s_waitcnt vmcnt(0)" ::: "memory");
        __builtin_amdgcn_s_barrier();

        const USHORT* sA = (const USHORT*)(smem + (size_t)(t & 3) * 32768);
        const USHORT* sB = sA + 8192;
        unsigned char* nb = smem + (size_t)((t + 2) & 3) * 32768;
        const size_t koff2 = (size_t)(t + 2) * 32;
        const bool pf = (t + 2 < NT);

        // ---- phase 0: reads (b, a-low) + half the prefetch, then 16 MFMA
        bf16x8 b[4], a0[4], a1[4];
        #pragma unroll
        for (int j = 0; j < 4; j++)
            b[j] = *(const bf16x8*)(sB + (wc * 64 + j * 16) * 32 + loff);
        #pragma unroll
        for (int i = 0; i < 4; i++)
            a0[i] = *(const bf16x8*)(sA + (wr * 128 + i * 16) * 32 + loff);
        if (pf) {
            gload_lds16(gA0 + koff2, nb + w * 1024);
            gload_lds16(gA1 + koff2, nb + 8192 + w * 1024);
        }
        __builtin_amdgcn_s_barrier();
        __builtin_amdgcn_s_setprio(1);
        #pragma unroll
        for (int i = 0; i < 4; i++)
            #pragma unroll
            for (int j = 0; j < 4; j++)
                acc[i][j] = __builtin_amdgcn_mfma_f32_16x16x32_bf16(a0[i], b[j], acc[i][j], 0, 0, 0);
        __builtin_amdgcn_s_setprio(0);

        // ---- phase 1: reads (a-high) + rest of prefetch, then 16 MFMA
        #pragma unroll
        for (int i = 0; i < 4; i++)
            a1[i] = *(const bf16x8*)(sA + (wr * 128 + 64 + i * 16) * 32 + loff);
        if (pf) {
            gload_lds16(gB0 + koff2, nb + 16384 + w * 1024);
            gload_lds16(gB1 + koff2, nb + 24576 + w * 1024);
        }
        __builtin_amdgcn_s_barrier();
        __builtin_amdgcn_s_setprio(1);
        #pragma unroll
        for (int i = 0; i < 4; i++)
            #pragma unroll
            for (int j = 0; j < 4; j++)
                acc[4 + i][j] = __builtin_amdgcn_mfma_f32_16x16x32_bf16(a1[i], b[j], acc[4 + i][j], 0, 0, 0);
        __builtin_amdgcn_s_setprio(0);
        // trailing fence of phase 1 == next boundary's vmcnt+barrier
    }

    // epilogue: per-wave private 16x68 f32 LDS slice in bytes [0,34816) =
    // ring slots 0/1.  Last tile uses slot 3 (NT=32 always here); slots 0/1
    // were last read 3 boundaries ago -> no cross-wave hazard, no barrier.
    float* eW = (float*)(smem + (size_t)w * 4352);
    const int erow = lane >> 2;          // 0..15
    const int ecq = lane & 3;            // 16-col quarter
    const int gcolb = tn + wc * 64 + ecq * 16;
    float bb[16];
    if constexpr (EPI == 1) {
        #pragma unroll
        for (int q = 0; q < 4; q++) {
            float4 bv = *(const float4*)&bias[gcolb + q * 4];
            bb[q*4+0] = bv.x; bb[q*4+1] = bv.y; bb[q*4+2] = bv.z; bb[q*4+3] = bv.w;
        }
    }
    #pragma unroll
    for (int i = 0; i < 8; i++) {
        #pragma unroll
        for (int j = 0; j < 4; j++)
            #pragma unroll
            for (int r = 0; r < 4; r++)
                eW[(quad * 4 + r) * 68 + j * 16 + fr] = acc[i][j][r];
        float v[16];
        #pragma unroll
        for (int q = 0; q < 4; q++) {
            float4 t4 = *(const float4*)&eW[erow * 68 + ecq * 16 + q * 4];
            v[q*4+0] = t4.x; v[q*4+1] = t4.y; v[q*4+2] = t4.z; v[q*4+3] = t4.w;
        }
        const int grow = tm + wr * 128 + i * 16 + erow;
        uint32_t pk[8];
        if constexpr (EPI == 1) {
            #pragma unroll
            for (int q = 0; q < 8; q++) {
                const float z0 = v[2*q]   + bb[2*q];
                const float z1 = v[2*q+1] + bb[2*q+1];
                const float u0 = z0 * (0.7978845608f + 0.035677408f * z0 * z0);
                const float u1 = z1 * (0.7978845608f + 0.035677408f * z1 * z1);
                const float s0 = __builtin_amdgcn_rcpf(1.f + fexp2(2.885390082f * u0));
                const float s1 = __builtin_amdgcn_rcpf(1.f + fexp2(2.885390082f * u1));
                const float g0 = z0 * (1.f - s0), g1 = z1 * (1.f - s1);
                pk[q] = (uint32_t)f2bf(g0) | ((uint32_t)f2bf(g1) << 16);
            }
            USHORT* op = (USHORT*)outp + (size_t)grow * N + gcolb;
            *(uint4*)op = make_uint4(pk[0], pk[1], pk[2], pk[3]);
            *(uint4*)(op + 8) = make_uint4(pk[4], pk[5], pk[6], pk[7]);
        } else {
            #pragma unroll
            for (int q = 0; q < 8; q++)
                pk[q] = (uint32_t)f2bf(v[2*q]) | ((uint32_t)f2bf(v[2*q+1]) << 16);
            USHORT* op = po + (size_t)grow * N + gcolb;
            *(uint4*)op = make_uint4(pk[0], pk[1], pk[2], pk[3]);
            *(uint4*)(op + 8) = make_uint4(pk[4], pk[5], pk[6], pk[7]);
        }
    }
}

// ---------------- FFN2 split-K reduce: out = sum(partials) + bias + extra ---
__global__ __launch_bounds__(256)
void ffn2_reduce(const USHORT* __restrict__ p01, const USHORT* __restrict__ p23,
                 const float* __restrict__ bias, const float* __restrict__ extra,
                 float* __restrict__ out)
{
    const size_t PS = (size_t)4096 * 1024;
    const size_t i = ((size_t)blockIdx.x * 256 + threadIdx.x) * 4;
    ushort4 a = *(const ushort4*)(p01 + i);
    ushort4 b = *(const ushort4*)(p01 + PS + i);
    ushort4 c = *(const ushort4*)(p23 + i);
    ushort4 d = *(const ushort4*)(p23 + PS + i);
    float4 bv = *(const float4*)(bias + (i & 1023));
    float4 ev = *(const float4*)(extra + i);
    float4 o;
    o.x = b2f(a.x) + b2f(b.x) + b2f(c.x) + b2f(d.x) + bv.x + ev.x;
    o.y = b2f(a.y) + b2f(b.y) + b2f(c.y) + b2f(d.y) + bv.y + ev.y;
    o.z = b2f(a.z) + b2f(b.z) + b2f(c.z) + b2f(d.z) + bv.z + ev.z;
    o.w = b2f(a.w) + b2f(b.w) + b2f(c.w) + b2f(d.w) + bv.w + ev.w;
    *(float4*)(out + i) = o;
}

// ---------------- bc = xn @ Wbc^T + bbc via MFMA: 64 tokens/block ----------
__global__ __launch_bounds__(256)
void bc_mfma(const USHORT* __restrict__ xn, const USHORT* __restrict__ WbcB,
             const float* __restrict__ bbc, float* __restrict__ bc)
{
    __shared__ __align__(16) USHORT As[64 * 32];
    __shared__ __align__(16) USHORT Bs[32 * 32];
    const int tid = threadIdx.x;
    const int lane = tid & 63;
    const int w = tid >> 6;
    const int tok0 = blockIdx.x * 64;

    const int srow = tid >> 2;
    const int scol = (tid & 3) * 8;
    const USHORT* gA = xn + (size_t)(tok0 + srow) * 1024 + scol;
    const USHORT* gB = WbcB + (size_t)srow * 1024 + scol;
    USHORT* lA = As + w * 512;
    USHORT* lB = Bs + w * 512;

    const int fr = lane & 15;
    const int fko = (lane >> 4) * 8;
    const int quad = lane >> 4;

    f32x4 acc[2];
    acc[0] = (f32x4){0.f, 0.f, 0.f, 0.f};
    acc[1] = (f32x4){0.f, 0.f, 0.f, 0.f};

    for (int k0 = 0; k0 < 1024; k0 += 32) {
        gload_lds16(gA + k0, lA);
        if (w < 2) gload_lds16(gB + k0, lB);
        __syncthreads();
        bf16x8 af = *(const bf16x8*)(As + (w * 16 + fr) * 32 + fko);
        bf16x8 b0 = *(const bf16x8*)(Bs + (fr) * 32 + fko);
        bf16x8 b1 = *(const bf16x8*)(Bs + (16 + fr) * 32 + fko);
        acc[0] = __builtin_amdgcn_mfma_f32_16x16x32_bf16(af, b0, acc[0], 0, 0, 0);
        acc[1] = __builtin_amdgcn_mfma_f32_16x16x32_bf16(af, b1, acc[1], 0, 0, 0);
        __syncthreads();
    }

    #pragma unroll
    for (int j = 0; j < 2; j++) {
        const int col = j * 16 + fr;
        const float bv = bbc[col];
        #pragma unroll
        for (int r = 0; r < 4; r++) {
            const int row = tok0 + w * 16 + quad * 4 + r;
            bc[(size_t)row * 32 + col] = acc[j][r] + bv;
        }
    }
}

// ---------------- selective scan v3: chunked parallel, lane=h, n in regs ----
#define SCAN_P 64
#define SCAN_T 32

__global__ __launch_bounds__(256)
void scan_pass1(const USHORT* __restrict__ xn, const float* __restrict__ delta,
                const float* __restrict__ bc, const float* __restrict__ Alog,
                float* __restrict__ sEnd, float* __restrict__ Ptot)
{
    const int tid = threadIdx.x;
    const int h = blockIdx.x * 256 + tid;
    const int b = blockIdx.y;
    const int p = blockIdx.z;
    const size_t tok0 = (size_t)b * 2048 + p * SCAN_T;

    __shared__ __align__(16) float sBC[SCAN_T][32];
    {
        int t = tid >> 3, q = (tid & 7) * 4;
        *(float4*)&sBC[t][q] = *(const float4*)(bc + (tok0 + t) * 32 + q);
    }

    float en[16], s[16], P[16];
    #pragma unroll
    for (int k = 0; k < 4; k++) {
        float4 a = *(const float4*)(Alog + h * 16 + k * 4);
        en[k*4+0] = -__expf(a.x) * 1.44269504f;
        en[k*4+1] = -__expf(a.y) * 1.44269504f;
        en[k*4+2] = -__expf(a.z) * 1.44269504f;
        en[k*4+3] = -__expf(a.w) * 1.44269504f;
    }
    #pragma unroll
    for (int n = 0; n < 16; n++) { s[n] = 0.f; P[n] = 1.f; }
    __syncthreads();

    const float* dp = delta + tok0 * 1024 + h;
    const USHORT* xp = xn + tok0 * 1024 + h;
    float d_c = dp[0];
    USHORT x_c = xp[0];
    for (int t = 0; t < SCAN_T; ++t) {
        const int tn = (t < SCAN_T - 1) ? t + 1 : t;
        float d_n = dp[(size_t)tn * 1024];
        USHORT x_n = xp[(size_t)tn * 1024];
        const float dx = d_c * b2f(x_c);
        #pragma unroll
        for (int k = 0; k < 4; k++) {
            float4 Bv = *(const float4*)&sBC[t][k*4];
            float bb[4] = { Bv.x, Bv.y, Bv.z, Bv.w };
            #pragma unroll
            for (int j = 0; j < 4; j++) {
                const int n = k*4 + j;
                const float dA = fexp2(d_c * en[n]);
                s[n] = fmaf(dA, s[n], dx * bb[j]);
                P[n] *= dA;
            }
        }
        d_c = d_n; x_c = x_n;
    }

    const size_t off = (size_t)p * 32768 + ((size_t)b * 1024 + h) * 16;
    #pragma unroll
    for (int k = 0; k < 4; k++) {
        *(float4*)(sEnd + off + k*4) = (float4){ s[k*4], s[k*4+1], s[k*4+2], s[k*4+3] };
        *(float4*)(Ptot + off + k*4) = (float4){ P[k*4], P[k*4+1], P[k*4+2], P[k*4+3] };
    }
}

__global__ __launch_bounds__(256)
void scan_mid(const float* __restrict__ sEnd, const float* __restrict__ Ptot,
              float* __restrict__ sIn)
{
    const int L = blockIdx.x * 256 + threadIdx.x;
    float s = 0.f;
    #pragma unroll 8
    for (int p = 0; p < SCAN_P; ++p) {
        const size_t off = (size_t)p * 32768 + L;
        sIn[off] = s;
        s = fmaf(Ptot[off], s, sEnd[off]);
    }
}

__global__ __launch_bounds__(256)
void scan_pass2(const float* __restrict__ x, const USHORT* __restrict__ xn,
                const float* __restrict__ delta, const float* __restrict__ bc,
                const float* __restrict__ Alog, const float* __restrict__ Dp,
                const float* __restrict__ sIn, float* __restrict__ ssm)
{
    const int tid = threadIdx.x;
    const int h = blockIdx.x * 256 + tid;
    const int b = blockIdx.y;
    const int p = blockIdx.z;
    const size_t tok0 = (size_t)b * 2048 + p * SCAN_T;

    __shared__ __align__(16) float sBC[SCAN_T][32];
    {
        int t = tid >> 3, q = (tid & 7) * 4;
        *(float4*)&sBC[t][q] = *(const float4*)(bc + (tok0 + t) * 32 + q);
    }

    float en[16], s[16];
    #pragma unroll
    for (int k = 0; k < 4; k++) {
        float4 a = *(const float4*)(Alog + h * 16 + k * 4);
        en[k*4+0] = -__expf(a.x) * 1.44269504f;
        en[k*4+1] = -__expf(a.y) * 1.44269504f;
        en[k*4+2] = -__expf(a.z) * 1.44269504f;
        en[k*4+3] = -__expf(a.w) * 1.44269504f;
    }
    const size_t off = (size_t)p * 32768 + ((size_t)b * 1024 + h) * 16;
    #pragma unroll
    for (int k = 0; k < 4; k++) {
        float4 v = *(const float4*)(sIn + off + k*4);
        s[k*4] = v.x; s[k*4+1] = v.y; s[k*4+2] = v.z; s[k*4+3] = v.w;
    }
    const float Dv = Dp[h];
    __syncthreads();

    const float* dp = delta + tok0 * 1024 + h;
    const USHORT* xp = xn + tok0 * 1024 + h;
    const float* xrp = x + tok0 * 1024 + h;
    float* op = ssm + tok0 * 1024 + h;

    float d_c = dp[0];
    USHORT x_c = xp[0];
    float xr_c = xrp[0];
    for (int t = 0; t < SCAN_T; ++t) {
        const int tn = (t < SCAN_T - 1) ? t + 1 : t;
        float d_n = dp[(size_t)tn * 1024];
        USHORT x_n = xp[(size_t)tn * 1024];
        float xr_n = xrp[(size_t)tn * 1024];
        const float xv = b2f(x_c);
        const float dx = d_c * xv;
        float y = 0.f;
        #pragma unroll
        for (int k = 0; k < 4; k++) {
            float4 Bv = *(const float4*)&sBC[t][k*4];
            float4 Cv = *(const float4*)&sBC[t][16 + k*4];
            float bb[4] = { Bv.x, Bv.y, Bv.z, Bv.w };
            float cc[4] = { Cv.x, Cv.y, Cv.z, Cv.w };
            #pragma unroll
            for (int j = 0; j < 4; j++) {
                const int n = k*4 + j;
                const float dA = fexp2(d_c * en[n]);
                s[n] = fmaf(dA, s[n], dx * bb[j]);
                y = fmaf(cc[j], s[n], y);
            }
        }
        op[(size_t)t * 1024] = xr_c + y + Dv * xv;
        d_c = d_n; x_c = x_n; xr_c = xr_n;
    }
}

extern "C" void kernel_launch(void* const* d_in, const int* in_sizes, int n_in,
                              void* d_out, int out_size, void* d_ws, size_t ws_size,
                              hipStream_t stream)
{
    const float* x    = (const float*)d_in[0];
    const float* ln1g = (const float*)d_in[1];
    const float* ln1b = (const float*)d_in[2];
    const float* Wd   = (const float*)d_in[3];
    const float* bd   = (const float*)d_in[4];
    const float* Wbc  = (const float*)d_in[5];
    const float* bbc  = (const float*)d_in[6];
    const float* Alog = (const float*)d_in[7];
    const float* Dp   = (const float*)d_in[8];
    const float* ln2g = (const float*)d_in[9];
    const float* ln2b = (const float*)d_in[10];
    const float* W1   = (const float*)d_in[11];
    const float* b1   = (const float*)d_in[12];
    const float* W2   = (const float*)d_in[13];
    const float* b2   = (const float*)d_in[14];
    float* out = (float*)d_out;

    char* ws = (char*)d_ws;
    const size_t MB = 1024 * 1024;
    float*  deltaW = (float*)(ws + 0);            // 16 MiB (4096x1024 f32)
    float*  ssmW   = (float*)(ws + 16 * MB);      // 16 MiB (4096x1024 f32)
    USHORT* xnW    = (USHORT*)(ws + 32 * MB);     //  8 MiB (4096x1024 bf16)
    USHORT* nrmW   = (USHORT*)(ws + 40 * MB);     //  8 MiB (4096x1024 bf16)
    USHORT* hffW   = (USHORT*)(ws + 48 * MB);     // 32 MiB (4096x4096 bf16)
    float*  bcW    = (float*)(ws + 80 * MB);      // 512 KiB (4096x32 f32)
    USHORT* WdB    = (USHORT*)(ws + 81 * MB);     //  2 MiB (1024x1024 bf16)
    USHORT* W1B    = (USHORT*)(ws + 83 * MB);     //  8 MiB (4096x1024 bf16)
    USHORT* W2B    = (USHORT*)(ws + 91 * MB);     //  8 MiB (1024x4096 bf16)
    USHORT* WbcB   = (USHORT*)(ws + 99 * MB);     // 64 KiB (32x1024 bf16)
    // scan scratch aliases hffW (dead until FFN1): 3 x 8 MiB
    float*  sEndW  = (float*)(ws + 48 * MB);
    float*  PtotW  = (float*)(ws + 56 * MB);
    float*  sInW   = (float*)(ws + 64 * MB);
    // FFN2 split-K partials alias deltaW (splits 0,1) and xnW/nrmW (2,3)
    USHORT* ffn2p01 = (USHORT*)(ws + 0);          // 16 MiB: 2 x 4096x1024 bf16
    USHORT* ffn2p23 = (USHORT*)(ws + 32 * MB);    // 16 MiB: 2 x 4096x1024 bf16

    // 0. convert weights f32 -> bf16
    f2b_kernel<<<1024, 256, 0, stream>>>(Wd, WdB, 1024 * 1024);
    f2b_kernel<<<4096, 256, 0, stream>>>(W1, W1B, 4096 * 1024);
    f2b_kernel<<<4096, 256, 0, stream>>>(W2, W2B, 1024 * 4096);
    f2b_kernel<<<32, 256, 0, stream>>>(Wbc, WbcB, 32 * 1024);
    // 1. xn = LN1(x)                         (bf16)
    ln_kernel<<<4096, 256, 0, stream>>>(x, ln1g, ln1b, xnW);
    // 2. delta = softplus(xn @ Wd^T + bd)    (f32), fused epilogue, no split-K
    gemm_bt<2><<<dim3(8, 32), 256, 0, stream>>>(xnW, WdB, bd, deltaW, nullptr, 4096, 1024, 1024, 1024, 1024);
    // 3. bc = xn @ Wbc^T + bbc               (f32), MFMA micro-GEMM
    bc_mfma<<<64, 256, 0, stream>>>(xnW, WbcB, bbc, bcW);
    // 4. ssm_out = x + scan(...) + D*xn      (f32), chunked parallel scan
    scan_pass1<<<dim3(4, 2, SCAN_P), 256, 0, stream>>>(xnW, deltaW, bcW, Alog, sEndW, PtotW);
    scan_mid<<<128, 256, 0, stream>>>(sEndW, PtotW, sInW);
    scan_pass2<<<dim3(4, 2, SCAN_P), 256, 0, stream>>>(x, xnW, deltaW, bcW, Alog, Dp, sInW, ssmW);
    // 5. normed = LN2(ssm_out)               (bf16)
    ln_kernel<<<4096, 256, 0, stream>>>(ssmW, ln2g, ln2b, nrmW);
    // 6. hff = gelu(normed @ W1^T + b1)      (bf16), 256^2 2-phase GEMM
    gemm256<1><<<dim3(16, 16), 512, 0, stream>>>(nrmW, W1B, b1, hffW, nullptr, 4096, 4096, 1024, 1024, 1024);
    // 7a. FFN2 split-K=4 partial GEMMs       (bf16 partials, grid.z = split)
    gemm256<3><<<dim3(4, 16, 4), 512, 0, stream>>>(hffW, W2B, nullptr, ffn2p01, ffn2p23, 4096, 1024, 1024, 4096, 4096);
    // 7b. out = sum(partials) + b2 + ssm_out (f32)
    ffn2_reduce<<<4096, 256, 0, stream>>>(ffn2p01, ffn2p23, b2, ssmW, out);

    (void)in_sizes; (void)n_in; (void)out_size; (void)ws_size;
}